// Round 5
// baseline (86.727 us; speedup 1.0000x reference)
//
#include <hip/hip_runtime.h>
#include <math.h>

// FocalCTCloss — MI355X (gfx950)
// T=160, N=128, C=6625, S=32, L=2S+1=65, blank=0
// Producer-consumer design:
//   clear_flags:  zero 128 sync flags (ws poisoned 0xAA once per session).
//   ctc_spin (512 blocks x 512 thr): 4 blocks per sample gather quarters of
//     the 33-unique-column lattice (5280 scattered loads). Quarters 1-3 ->
//     ws + threadfence + atomicAdd(flag). Quarter 0 -> LDS directly, spins
//     on flag==3, stages quarters 1-3 from ws (L2/L3), then wave 0 runs the
//     159-step DPP-shift alpha recursion in log2 domain.
//   focal_reduce: deterministic reduce + focal transform.

#define TT 160
#define NN 128
#define CC 6625
#define SS 32
#define JJ 33              // unique labels per (n,t): blank + 32
#define NTJ (TT * JJ)      // 5280 per sample
#define QTR 1320           // NTJ / 4
#define NEGV  (-1e30f)
#define LOG2E 1.4426950408889634f
#define LN2   0.6931471805599453f

// wave64 shift-up-by-1 via DPP: row_shr:1 + row_bcast15 patch for lanes 16k.
// Lane 0 result is garbage — callers mask explicitly.
__device__ __forceinline__ float dpp_up1(float x, bool row0lane) {
    int xi = __float_as_int(x);
    int shr = __builtin_amdgcn_update_dpp(xi, xi, 0x111, 0xf, 0xf, false); // row_shr:1
    int bc  = __builtin_amdgcn_update_dpp(xi, xi, 0x142, 0xf, 0xf, false); // row_bcast15
    return __int_as_float(row0lane ? bc : shr);
}

__global__ __launch_bounds__(128) void clear_flags(int* __restrict__ flags) {
    flags[threadIdx.x] = 0;
}

__global__ __launch_bounds__(512) void ctc_spin_kernel(
    const float* __restrict__ log_probs,      // [T, N, C]
    const int*   __restrict__ targets,        // [N, S]
    const int*   __restrict__ input_lengths,  // [N]
    const int*   __restrict__ target_lengths, // [N]
    int*         __restrict__ flags,          // [N]
    float*       __restrict__ lp_ws,          // [N][NTJ]
    float*       __restrict__ per_sample)     // [N]
{
    const int bid = blockIdx.x;
    const int n   = bid >> 2;          // sample
    const int q   = bid & 3;           // quarter
    const int tid = threadIdx.x;

    __shared__ float lp[NTJ];          // 21.1 KB (used by q==0 blocks)
    __shared__ int   lab[JJ];

    if (tid < JJ) lab[tid] = (tid == 0) ? 0 : targets[n * SS + tid - 1];
    __syncthreads();

    // ---- gather own quarter (1320 scattered loads over 512 threads) ----
    float* wsn = lp_ws + (size_t)n * NTJ;
    const size_t rowbase = (size_t)n * CC;
#pragma unroll
    for (int k = 0; k < 3; ++k) {
        const int i = q * QTR + tid + k * 512;
        if (i < (q + 1) * QTR) {
            const int t = i / JJ;
            const int j = i - t * JJ;
            const float val = log_probs[(size_t)t * (NN * CC) + rowbase + lab[j]] * LOG2E;
            if (q == 0) lp[i] = val;       // consumer keeps own quarter in LDS
            else        wsn[i] = val;      // producers publish via ws
        }
    }
    __syncthreads();

    if (q != 0) {
        if (tid == 0) { __threadfence(); atomicAdd(&flags[n], 1); }
        return;
    }

    // ---- consumer: wait for the other three quarters ----
    if (tid == 0) {
        while (__hip_atomic_load(&flags[n], __ATOMIC_ACQUIRE,
                                 __HIP_MEMORY_SCOPE_AGENT) < 3)
            __builtin_amdgcn_s_sleep(1);
        __threadfence();
    }
    __syncthreads();

    // stage quarters 1-3 from ws (float4: indices 330..1319)
    const float4* s4 = (const float4*)wsn;
    float4* d4 = (float4*)lp;
#pragma unroll
    for (int k = 0; k < 2; ++k) {
        const int i = QTR / 4 + tid + k * 512;
        if (i < NTJ / 4) d4[i] = s4[i];
    }
    __syncthreads();

    if (tid >= 64) return;             // wave 0 only; no more barriers
    const int lane = tid;

    const int tl = target_lengths[n];
    const int Lv = 2 * tl + 1;
    const int slot = (lane & 1) ? (1 + (lane >> 1)) : 0;
    const bool skip = (lane & 1) && (lane >= 3) &&
                      (lab[1 + (lane >> 1)] != lab[lane >> 1]);
    const bool validl   = lane < Lv;
    const bool valid64  = 64 < Lv;
    const bool row0lane = (lane & 15) == 0;

    float v = NEGV;
    if (lane == 0) v = lp[0];          // t=0, blank
    if (lane == 1) v = lp[1];          // t=0, first label
    float e = NEGV;                    // l=64 rides on lane 63

    const int ilen = input_lengths[n];
    const int Tlim = (ilen < TT) ? ilen : TT;

    for (int t = 1; t < Tlim; ++t) {
        const float u1 = dpp_up1(v, row0lane);   // v[lane-1]
        const float u2 = dpp_up1(u1, row0lane);  // v[lane-2]
        const float a2 = (lane == 0) ? NEGV : u1;
        const float a3 = skip ? u2 : NEGV;

        const float lpt64 = lp[t * JJ];          // blank slot, broadcast
        const float me = fmaxf(e, v);
        const float ne = me + log2f(exp2f(e - me) + exp2f(v - me)) + lpt64;

        const float m  = fmaxf(v, fmaxf(a2, a3));
        const float nv = m + log2f(exp2f(v - m) + exp2f(a2 - m) + exp2f(a3 - m))
                           + lp[t * JJ + slot];

        v = validl  ? nv : NEGV;
        e = valid64 ? ne : NEGV;
    }

    const int i1 = 2 * tl;
    const int i2 = 2 * tl - 1;
    const float A1 = (i1 == 64) ? __shfl(e, 63) : __shfl(v, i1);
    const float A2 = __shfl(v, i2);
    if (lane == 0) {
        const float m = fmaxf(A1, A2);
        float loss = -LN2 * (m + log2f(exp2f(A1 - m) + exp2f(A2 - m)));
        if (loss > 1e29f) loss = 0.0f;           // zero_infinity
        per_sample[n] = loss / (float)tl;
    }
}

__global__ __launch_bounds__(128) void focal_reduce_kernel(
    const float* __restrict__ per_sample, float* __restrict__ out)
{
    __shared__ float s[NN];
    int tid = threadIdx.x;
    s[tid] = per_sample[tid];
    __syncthreads();
    for (int off = NN / 2; off > 0; off >>= 1) {
        if (tid < off) s[tid] += s[tid + off];
        __syncthreads();
    }
    if (tid == 0) {
        float mean = s[0] / (float)NN;
        float pp = expf(-mean);
        float om = 1.0f - pp;
        out[0] = 0.5f * om * om * mean;          // ALPHA=0.5, GAMMA=2.0
    }
}

extern "C" void kernel_launch(void* const* d_in, const int* in_sizes, int n_in,
                              void* d_out, int out_size, void* d_ws, size_t ws_size,
                              hipStream_t stream) {
    const float* log_probs      = (const float*)d_in[0];
    const int*   targets        = (const int*)d_in[1];
    const int*   input_lengths  = (const int*)d_in[2];
    const int*   target_lengths = (const int*)d_in[3];
    float* out = (float*)d_out;

    int*   flags      = (int*)d_ws;                          // 128 ints
    float* per_sample = (float*)((char*)d_ws + 2048);        // 128 floats
    float* lp_ws      = (float*)((char*)d_ws + 4096);        // N*NTJ floats

    clear_flags<<<1, 128, 0, stream>>>(flags);
    ctc_spin_kernel<<<NN * 4, 512, 0, stream>>>(log_probs, targets,
                                                input_lengths, target_lengths,
                                                flags, lp_ws, per_sample);
    focal_reduce_kernel<<<1, NN, 0, stream>>>(per_sample, out);
}

// Round 6
// 39.660 us; speedup vs baseline: 2.1867x; 2.1867x over previous
//
#include <hip/hip_runtime.h>
#include <math.h>

// FocalCTCloss — MI355X (gfx950)
// T=160, N=128, C=6625, S=32, L=2S+1=65, blank=0
// R6: revert R5's spin design (regressed 48->87). R4 fused structure +
// software-pipelined chunks: 5 chunks of 32 t-steps; waves 1-15 gather
// chunk c+1 while wave 0 runs the DPP-shift alpha recursion over chunk c.
// One __syncthreads per chunk. Gather is device random-line-throughput
// bound (~43MB unique 64B lines); scan hides under it.

#define TT 160
#define NN 128
#define CC 6625
#define SS 32
#define JJ 33              // unique labels per (n,t): blank + 32
#define NTJ (TT * JJ)      // 5280
#define CHT 32             // t-steps per chunk
#define CHE (CHT * JJ)     // 1056 elements per chunk
#define NCH 5              // 160 / 32
#define NEGV  (-1e30f)
#define LOG2E 1.4426950408889634f
#define LN2   0.6931471805599453f

// wave64 shift-up-by-1 via DPP: row_shr:1 + row_bcast15 patch for lanes 16k.
// Lane 0 result is garbage — callers mask explicitly.
__device__ __forceinline__ float dpp_up1(float x, bool row0lane) {
    int xi = __float_as_int(x);
    int shr = __builtin_amdgcn_update_dpp(xi, xi, 0x111, 0xf, 0xf, false); // row_shr:1
    int bc  = __builtin_amdgcn_update_dpp(xi, xi, 0x142, 0xf, 0xf, false); // row_bcast15
    return __int_as_float(row0lane ? bc : shr);
}

__global__ __launch_bounds__(1024) void ctc_fused_kernel(
    const float* __restrict__ log_probs,      // [T, N, C]
    const int*   __restrict__ targets,        // [N, S]
    const int*   __restrict__ input_lengths,  // [N]
    const int*   __restrict__ target_lengths, // [N]
    float*       __restrict__ per_sample)     // [N]
{
    const int n   = blockIdx.x;
    const int tid = threadIdx.x;

    __shared__ float lp[NTJ];       // 21.1 KB, log2-scaled unique columns
    __shared__ int   lab[JJ];       // slot 0 = blank, slot j = targets[j-1]

    if (tid < JJ) lab[tid] = (tid == 0) ? 0 : targets[n * SS + tid - 1];
    __syncthreads();

    const size_t rowbase = (size_t)n * CC;

    // ---- prologue: gather chunk 0 (t = 0..31), all 1024 threads ----
#pragma unroll
    for (int k = 0; k < 2; ++k) {
        const int i = tid + k * 1024;
        if (i < CHE) {
            const int t = i / JJ;
            const int j = i - t * JJ;
            lp[i] = log_probs[(size_t)t * (NN * CC) + rowbase + lab[j]] * LOG2E;
        }
    }
    __syncthreads();

    // ---- scan state (wave 0) ----
    const int lane = tid;                       // used only when tid < 64
    const int tl = target_lengths[n];
    const int Lv = 2 * tl + 1;
    const int slot = (lane & 1) ? (1 + (lane >> 1)) : 0;
    const bool skip = (lane & 1) && (lane >= 3) &&
                      (lab[(lane >> 1) < SS ? 1 + (lane >> 1) : 1] !=
                       lab[(lane >> 1) < 1 ? 0 : (lane >> 1)]);
    const bool validl   = lane < Lv;
    const bool valid64  = 64 < Lv;
    const bool row0lane = (lane & 15) == 0;

    float v = NEGV;
    if (lane == 0) v = lp[0];                   // t=0, blank
    if (lane == 1) v = lp[1];                   // t=0, first label
    float e = NEGV;                             // l=64 rides on lane 63

    const int ilen = input_lengths[n];
    const int Tlim = (ilen < TT) ? ilen : TT;

    // ---- pipelined chunks ----
    for (int c = 0; c < NCH; ++c) {
        // waves 1..15: gather chunk c+1
        if (tid >= 64 && c + 1 < NCH) {
            const int base = (c + 1) * CHE;
#pragma unroll
            for (int k = 0; k < 2; ++k) {
                const int r = (tid - 64) + k * 960;
                if (r < CHE) {
                    const int i = base + r;
                    const int t = i / JJ;
                    const int j = i - t * JJ;
                    lp[i] = log_probs[(size_t)t * (NN * CC) + rowbase + lab[j]] * LOG2E;
                }
            }
        }
        // wave 0: scan chunk c
        if (tid < 64) {
            const int t_lo = (c == 0) ? 1 : c * CHT;
            int t_hi = (c + 1) * CHT;
            if (t_hi > Tlim) t_hi = Tlim;
            for (int t = t_lo; t < t_hi; ++t) {
                const float u1 = dpp_up1(v, row0lane);   // v[lane-1]
                const float u2 = dpp_up1(u1, row0lane);  // v[lane-2]
                const float a2 = (lane == 0) ? NEGV : u1;
                const float a3 = skip ? u2 : NEGV;

                const float lpt64 = lp[t * JJ];          // blank slot, broadcast
                const float me = fmaxf(e, v);
                const float ne = me + log2f(exp2f(e - me) + exp2f(v - me)) + lpt64;

                const float m  = fmaxf(v, fmaxf(a2, a3));
                const float nv = m + log2f(exp2f(v - m) + exp2f(a2 - m) + exp2f(a3 - m))
                                   + lp[t * JJ + slot];

                v = validl  ? nv : NEGV;
                e = valid64 ? ne : NEGV;
            }
        }
        __syncthreads();
    }

    if (tid >= 64) return;

    const int i1 = 2 * tl;
    const int i2 = 2 * tl - 1;
    const float A1 = (i1 == 64) ? __shfl(e, 63) : __shfl(v, i1);
    const float A2 = __shfl(v, i2);
    if (lane == 0) {
        const float m = fmaxf(A1, A2);
        float loss = -LN2 * (m + log2f(exp2f(A1 - m) + exp2f(A2 - m)));
        if (loss > 1e29f) loss = 0.0f;           // zero_infinity
        per_sample[n] = loss / (float)tl;
    }
}

__global__ __launch_bounds__(128) void focal_reduce_kernel(
    const float* __restrict__ per_sample, float* __restrict__ out)
{
    __shared__ float s[NN];
    int tid = threadIdx.x;
    s[tid] = per_sample[tid];
    __syncthreads();
    for (int off = NN / 2; off > 0; off >>= 1) {
        if (tid < off) s[tid] += s[tid + off];
        __syncthreads();
    }
    if (tid == 0) {
        float mean = s[0] / (float)NN;
        float pp = expf(-mean);
        float om = 1.0f - pp;
        out[0] = 0.5f * om * om * mean;          // ALPHA=0.5, GAMMA=2.0
    }
}

extern "C" void kernel_launch(void* const* d_in, const int* in_sizes, int n_in,
                              void* d_out, int out_size, void* d_ws, size_t ws_size,
                              hipStream_t stream) {
    const float* log_probs      = (const float*)d_in[0];
    const int*   targets        = (const int*)d_in[1];
    const int*   input_lengths  = (const int*)d_in[2];
    const int*   target_lengths = (const int*)d_in[3];
    float* out        = (float*)d_out;
    float* per_sample = (float*)d_ws;    // 128 floats

    ctc_fused_kernel<<<NN, 1024, 0, stream>>>(log_probs, targets, input_lengths,
                                              target_lengths, per_sample);
    focal_reduce_kernel<<<1, NN, 0, stream>>>(per_sample, out);
}